// Round 1
// baseline (2369.277 us; speedup 1.0000x reference)
//
#include <hip/hip_runtime.h>
#include <hip/hip_bf16.h>
#include <cstddef>

// ---------------------------------------------------------------------------
// Constants for this problem: B=4, L=2048, D=1024
// ---------------------------------------------------------------------------
#define BB 4
#define LL 2048
#define DD 1024
#define MM (BB*LL)          // 8192 tokens

// ---------------------------------------------------------------------------
// RMSNorm: one block per row of 1024 floats
// ---------------------------------------------------------------------------
__global__ __launch_bounds__(256) void rmsnorm_kernel(
    const float* __restrict__ in, const float* __restrict__ w,
    float* __restrict__ out)
{
    const int row = blockIdx.x;
    const float4* ip = (const float4*)(in + (size_t)row * DD);
    float4 v = ip[threadIdx.x];
    float ss = v.x*v.x + v.y*v.y + v.z*v.z + v.w*v.w;
    #pragma unroll
    for (int off = 32; off > 0; off >>= 1) ss += __shfl_down(ss, off, 64);
    __shared__ float sums[4];
    const int wid = threadIdx.x >> 6;
    if ((threadIdx.x & 63) == 0) sums[wid] = ss;
    __syncthreads();
    const float tot = sums[0] + sums[1] + sums[2] + sums[3];
    const float scale = rsqrtf(tot * (1.0f / (float)DD) + 1e-8f);
    const float4 wv = ((const float4*)w)[threadIdx.x];
    float4 o;
    o.x = v.x * scale * wv.x; o.y = v.y * scale * wv.y;
    o.z = v.z * scale * wv.z; o.w = v.w * scale * wv.w;
    ((float4*)(out + (size_t)row * DD))[threadIdx.x] = o;
}

// ---------------------------------------------------------------------------
// Generic fp32 GEMM: C(M,N) = epi(A(M,K) @ W(N,K)^T + bias) [+ res]
// EPI: 0 = bias only, 1 = bias + residual, 2 = bias + tanh-GELU
// Tile 64x64, BK=16, 256 threads, 4x4 per thread.
// ---------------------------------------------------------------------------
__device__ __forceinline__ float gelu_tanh(float x) {
    const float c = 0.7978845608028654f;   // sqrt(2/pi)
    float t = tanhf(c * (x + 0.044715f * x * x * x));
    return 0.5f * x * (1.0f + t);
}

template<int EPI>
__global__ __launch_bounds__(256) void gemm_wt_kernel(
    const float* __restrict__ A,    // (M,K) row-major
    const float* __restrict__ W,    // (N,K) row-major
    const float* __restrict__ bias, // (N)
    const float* __restrict__ res,  // (M,N) or nullptr
    float* __restrict__ C,          // (M,N)
    int M, int N, int K)
{
    __shared__ __align__(16) float As[16][68];
    __shared__ __align__(16) float Bs[16][68];
    const int bm = blockIdx.y * 64;
    const int bn = blockIdx.x * 64;
    const int tid = threadIdx.x;
    const int tx = tid & 15;       // col group
    const int ty = tid >> 4;       // row group
    const int lrow = tid >> 2;     // 0..63  (loader)
    const int lkq  = tid & 3;      // 0..3   (float4 index within 16 k's)

    float acc[4][4] = {};

    for (int k0 = 0; k0 < K; k0 += 16) {
        float4 av = *(const float4*)(&A[(size_t)(bm + lrow) * K + k0 + lkq * 4]);
        float4 bv = *(const float4*)(&W[(size_t)(bn + lrow) * K + k0 + lkq * 4]);
        As[lkq*4+0][lrow] = av.x; As[lkq*4+1][lrow] = av.y;
        As[lkq*4+2][lrow] = av.z; As[lkq*4+3][lrow] = av.w;
        Bs[lkq*4+0][lrow] = bv.x; Bs[lkq*4+1][lrow] = bv.y;
        Bs[lkq*4+2][lrow] = bv.z; Bs[lkq*4+3][lrow] = bv.w;
        __syncthreads();
        #pragma unroll
        for (int kk = 0; kk < 16; ++kk) {
            float4 a = *(const float4*)(&As[kk][ty * 4]);
            float4 b = *(const float4*)(&Bs[kk][tx * 4]);
            float ar[4] = {a.x, a.y, a.z, a.w};
            float br[4] = {b.x, b.y, b.z, b.w};
            #pragma unroll
            for (int i = 0; i < 4; ++i)
                #pragma unroll
                for (int j = 0; j < 4; ++j)
                    acc[i][j] += ar[i] * br[j];
        }
        __syncthreads();
    }

    const float4 bv = *(const float4*)(&bias[bn + tx * 4]);
    const float br[4] = {bv.x, bv.y, bv.z, bv.w};
    #pragma unroll
    for (int i = 0; i < 4; ++i) {
        const int m = bm + ty * 4 + i;
        float o[4];
        #pragma unroll
        for (int j = 0; j < 4; ++j) {
            float v = acc[i][j] + br[j];
            if constexpr (EPI == 2) v = gelu_tanh(v);
            o[j] = v;
        }
        if constexpr (EPI == 1) {
            const float4 rv = *(const float4*)(&res[(size_t)m * N + bn + tx * 4]);
            o[0] += rv.x; o[1] += rv.y; o[2] += rv.z; o[3] += rv.w;
        }
        float4 ov = make_float4(o[0], o[1], o[2], o[3]);
        *(float4*)(&C[(size_t)m * N + bn + tx * 4]) = ov;
    }
}

// ---------------------------------------------------------------------------
// Depthwise causal k=3 short filter on u (B,L,3D), producing
//   x0  (B,L,D)   = conv channels [0,D)
//   vin (B,D,L)   = conv[2D..3D) * conv[D..2D)    (v * x1 gate)
// ---------------------------------------------------------------------------
__global__ __launch_bounds__(256) void shortfilter_kernel(
    const float* __restrict__ u, const float* __restrict__ sw,
    const float* __restrict__ sb, float* __restrict__ x0,
    float* __restrict__ vin)
{
    const int bl = blockIdx.x;          // b*L + l
    const int b = bl >> 11;
    const int l = bl & (LL - 1);
    const float* u0 = u + (size_t)bl * (3 * DD);
    #pragma unroll
    for (int i = 0; i < 4; ++i) {
        const int d = threadIdx.x + (i << 8);
        float vals[3];
        #pragma unroll
        for (int g = 0; g < 3; ++g) {
            const int c = (g << 10) + d;
            float acc = sw[c * 3 + 2] * u0[c] + sb[c];
            if (l >= 1) acc += sw[c * 3 + 1] * u0[c - 3 * DD];
            if (l >= 2) acc += sw[c * 3 + 0] * u0[c - 6 * DD];
            vals[g] = acc;
        }
        x0[(size_t)bl * DD + d] = vals[0];
        vin[((size_t)(b << 10) + d) * LL + l] = vals[2] * vals[1];
    }
}

// ---------------------------------------------------------------------------
// Implicit filter MLP -> kfilt (D,L). One block per position l.
// ---------------------------------------------------------------------------
__global__ __launch_bounds__(256) void filtergen_kernel(
    const float* __restrict__ w1, const float* __restrict__ b1,
    const float* __restrict__ f1, const float* __restrict__ w2,
    const float* __restrict__ b2, const float* __restrict__ f2,
    const float* __restrict__ w3, float* __restrict__ kfilt)
{
    __shared__ float h1[64];
    __shared__ float h2[64];
    const int l = blockIdx.x;
    const float t = (float)l / (float)(LL - 1);
    const float ang = 1e-4f * 6.283185307179586f * (float)l / (float)LL;
    const float z0 = t, z1 = cosf(ang), z2 = -sinf(ang);
    const int tid = threadIdx.x;
    if (tid < 64) {
        float s = w1[tid*3+0]*z0 + w1[tid*3+1]*z1 + w1[tid*3+2]*z2 + b1[tid];
        h1[tid] = sinf(f1[tid] * s);
    }
    __syncthreads();
    if (tid < 64) {
        float s = b2[tid];
        #pragma unroll 8
        for (int j = 0; j < 64; ++j) s += w2[tid*64+j] * h1[j];
        h2[tid] = sinf(f2[tid] * s);
    }
    __syncthreads();
    const float min_decay = -3.0701134573253944f;   // ln(1e-2)/1.5
    const float max_decay = -15.350567286626972f;   // ln(1e-2)/0.3
    #pragma unroll
    for (int i = 0; i < 4; ++i) {
        const int d = tid + (i << 8);
        float s = 0.f;
        #pragma unroll 8
        for (int j = 0; j < 64; ++j) s += w3[d*64+j] * h2[j];
        const float delta = fabsf(min_decay + (max_decay - min_decay) * (float)d / (float)(DD - 1));
        kfilt[(size_t)d * LL + l] = s * expf(-t * delta);
    }
}

// ---------------------------------------------------------------------------
// 4096-point complex Stockham radix-2 FFT in LDS (12 stages, autosort).
// sign = -1 forward, +1 unnormalized inverse. 256 threads, 8 butterflies each.
// Returns index of buffer holding the result (== start after 12 stages).
// ---------------------------------------------------------------------------
__device__ __forceinline__ int fft4096_stages(float2 (*bufs)[4096], int cur, float sign)
{
    int n = 4096;
    int ls = 0;                       // log2(stride)
    while (n > 1) {
        const int m = n >> 1;
        const float theta = sign * 6.283185307179586f / (float)n;
        float2* __restrict__ src = bufs[cur];
        float2* __restrict__ dst = bufs[cur ^ 1];
        const int s = 1 << ls;
        #pragma unroll
        for (int it = 0; it < 8; ++it) {
            const int idx = (int)threadIdx.x + (it << 8);   // 0..2047
            const int p = idx >> ls;
            const int q = idx & (s - 1);
            const float2 a = src[q + (p << ls)];
            const float2 b = src[q + ((p + m) << ls)];
            float sn, cs;
            __sincosf(theta * (float)p, &sn, &cs);
            const float rx = a.x - b.x, ry = a.y - b.y;
            dst[q + (p << (ls + 1))]     = make_float2(a.x + b.x, a.y + b.y);
            dst[q + (p << (ls + 1)) + s] = make_float2(rx * cs - ry * sn,
                                                       rx * sn + ry * cs);
        }
        __syncthreads();
        cur ^= 1;
        n = m;
        ++ls;
    }
    return cur;
}

// FFT of the implicit filter rows: Kf[d,:] = FFT_4096(k[d,:] padded) / 4096
__global__ __launch_bounds__(256) void kfft_kernel(
    const float* __restrict__ kfilt, float2* __restrict__ Kf)
{
    __shared__ float2 fb[2][4096];
    const int d = blockIdx.x;
    const float* kr = kfilt + (size_t)d * LL;
    const float inv = 1.0f / 4096.0f;
    for (int i = threadIdx.x; i < LL; i += 256) {
        fb[0][i]      = make_float2(kr[i] * inv, 0.f);
        fb[0][i + LL] = make_float2(0.f, 0.f);
    }
    __syncthreads();
    const int cur = fft4096_stages(fb, 0, -1.0f);
    float2* out = Kf + (size_t)d * 4096;
    for (int i = threadIdx.x; i < 4096; i += 256) out[i] = fb[cur][i];
}

// In-place causal long conv per (b,d) row: vio <- conv(vio, k) + bias*vio
__global__ __launch_bounds__(256) void fftconv_kernel(
    float* __restrict__ vio, const float2* __restrict__ Kf,
    const float* __restrict__ fbias)
{
    __shared__ float2 fb[2][4096];
    const int row = blockIdx.x;           // b*D + d
    const int d = row & (DD - 1);
    float* v = vio + (size_t)row * LL;
    for (int i = threadIdx.x; i < LL; i += 256) {
        fb[0][i]      = make_float2(v[i], 0.f);
        fb[0][i + LL] = make_float2(0.f, 0.f);
    }
    __syncthreads();
    int cur = fft4096_stages(fb, 0, -1.0f);
    const float2* kf = Kf + (size_t)d * 4096;
    for (int i = threadIdx.x; i < 4096; i += 256) {
        const float2 a = fb[cur][i];
        const float2 k = kf[i];
        fb[cur][i] = make_float2(a.x * k.x - a.y * k.y,
                                 a.x * k.y + a.y * k.x);
    }
    __syncthreads();
    cur = fft4096_stages(fb, cur, 1.0f);   // unnormalized inverse
    const float bias = fbias[d];
    for (int i = threadIdx.x; i < LL; i += 256) {
        v[i] = fb[cur][i].x + bias * v[i];
    }
}

// ---------------------------------------------------------------------------
// gated(B,L,D) = y(B,D,L) * x0(B,L,D)   -- LDS-tiled 32x32 transpose
// ---------------------------------------------------------------------------
__global__ __launch_bounds__(256) void gate_transpose_kernel(
    const float* __restrict__ y, const float* __restrict__ x0,
    float* __restrict__ g)
{
    __shared__ float tile[32][33];
    const int b  = blockIdx.z;
    const int l0 = blockIdx.x * 32;
    const int d0 = blockIdx.y * 32;
    const int tx  = threadIdx.x & 31;
    const int tyb = threadIdx.x >> 5;    // 0..7
    #pragma unroll
    for (int i = 0; i < 4; ++i) {
        const int dy = tyb + i * 8;
        tile[dy][tx] = y[((size_t)(b * DD + d0 + dy)) * LL + l0 + tx];
    }
    __syncthreads();
    #pragma unroll
    for (int i = 0; i < 4; ++i) {
        const int ly = tyb + i * 8;
        const size_t idx = ((size_t)(b * LL + l0 + ly)) * DD + d0 + tx;
        g[idx] = tile[tx][ly] * x0[idx];
    }
}

// ---------------------------------------------------------------------------
// Launch
// ---------------------------------------------------------------------------
extern "C" void kernel_launch(void* const* d_in, const int* in_sizes, int n_in,
                              void* d_out, int out_size, void* d_ws, size_t ws_size,
                              hipStream_t stream)
{
    (void)in_sizes; (void)n_in; (void)out_size; (void)ws_size;
    const float* x   = (const float*)d_in[0];
    const float* nw0 = (const float*)d_in[1];
    const float* ipw = (const float*)d_in[2];
    const float* ipb = (const float*)d_in[3];
    const float* sfw = (const float*)d_in[4];
    const float* sfb = (const float*)d_in[5];
    const float* w1  = (const float*)d_in[6];
    const float* b1  = (const float*)d_in[7];
    const float* f1  = (const float*)d_in[8];
    const float* w2  = (const float*)d_in[9];
    const float* b2  = (const float*)d_in[10];
    const float* f2  = (const float*)d_in[11];
    const float* w3  = (const float*)d_in[12];
    const float* fbv = (const float*)d_in[13];
    const float* opw = (const float*)d_in[14];
    const float* opb = (const float*)d_in[15];
    const float* nw1 = (const float*)d_in[16];
    const float* fw1 = (const float*)d_in[17];
    const float* fb1 = (const float*)d_in[18];
    const float* fw2 = (const float*)d_in[19];
    const float* fb2 = (const float*)d_in[20];
    float* out = (float*)d_out;

    float* ws    = (float*)d_ws;
    float* u     = ws;                        // (B,L,3D)     25,165,824 f  (also ffn mid later)
    float* bufA  = ws + 25165824;             // xn -> gated   8,388,608 f
    float* bufB  = ws + 33554432;             // x0 -> h       8,388,608 f
    float* bufC  = ws + 41943040;             // vin -> y -> hn 8,388,608 f
    float* kfilt = ws + 50331648;             // (D,L)         2,097,152 f
    float2* Kf   = (float2*)(ws + 52428800);  // (D,4096) cplx 8,388,608 f
    // total: 60,817,408 floats = 243.3 MB

    // 1. xn = rmsnorm(x, norm_in_w)
    rmsnorm_kernel<<<MM, 256, 0, stream>>>(x, nw0, bufA);
    // 2. u = xn @ in_proj_w^T + b           (M=8192, N=3072, K=1024)
    gemm_wt_kernel<0><<<dim3(3072/64, MM/64), 256, 0, stream>>>(
        bufA, ipw, ipb, nullptr, u, MM, 3*DD, DD);
    // 3. short filter -> x0 (B,L,D), vin (B,D,L)
    shortfilter_kernel<<<MM, 256, 0, stream>>>(u, sfw, sfb, bufB, bufC);
    // 4. implicit filter -> kfilt (D,L)
    filtergen_kernel<<<LL, 256, 0, stream>>>(w1, b1, f1, w2, b2, f2, w3, kfilt);
    // 5. Kf = FFT(kfilt)/4096
    kfft_kernel<<<DD, 256, 0, stream>>>(kfilt, Kf);
    // 6. vin <- causal_conv(vin, k) + filter_bias * vin   (in place)
    fftconv_kernel<<<BB*DD, 256, 0, stream>>>(bufC, Kf, fbv);
    // 7. gated(B,L,D) = y * x0
    gate_transpose_kernel<<<dim3(LL/32, DD/32, BB), 256, 0, stream>>>(bufC, bufB, bufA);
    // 8. h = gated @ out_proj_w^T + b + x   (M=8192, N=1024, K=1024)
    gemm_wt_kernel<1><<<dim3(DD/64, MM/64), 256, 0, stream>>>(
        bufA, opw, opb, x, bufB, MM, DD, DD);
    // 9. hn = rmsnorm(h, norm_w)
    rmsnorm_kernel<<<MM, 256, 0, stream>>>(bufB, nw1, bufC);
    // 10. mid = gelu(hn @ ffn_w1^T + b)     (M=8192, N=2048, K=1024)
    gemm_wt_kernel<2><<<dim3(2*DD/64, MM/64), 256, 0, stream>>>(
        bufC, fw1, fb1, nullptr, u, MM, 2*DD, DD);
    // 11. out = mid @ ffn_w2^T + b + h      (M=8192, N=1024, K=2048)
    gemm_wt_kernel<1><<<dim3(DD/64, MM/64), 256, 0, stream>>>(
        u, fw2, fb2, bufB, out, MM, DD, 2*DD);
}

// Round 2
// 894.353 us; speedup vs baseline: 2.6492x; 2.6492x over previous
//
#include <hip/hip_runtime.h>
#include <hip/hip_bf16.h>
#include <cstddef>

// ---------------------------------------------------------------------------
// Constants for this problem: B=4, L=2048, D=1024
// ---------------------------------------------------------------------------
#define BB 4
#define LL 2048
#define DD 1024
#define MM (BB*LL)          // 8192 tokens
#define KF_STRIDE 2056      // complex elements per Kf row (>= 2049, 16B-aligned)

typedef __bf16 bf16_t;
typedef __attribute__((ext_vector_type(8))) __bf16 bf16x8;
typedef __attribute__((ext_vector_type(4))) __bf16 bf16x4;
typedef __attribute__((ext_vector_type(4))) float f32x4;

// async global->LDS, 16 bytes per lane (global_load_lds_dwordx4)
#define GLD_LDS16(gp, lp) __builtin_amdgcn_global_load_lds(                 \
    (const __attribute__((address_space(1))) unsigned int*)(gp),            \
    (__attribute__((address_space(3))) unsigned int*)(lp), 16, 0, 0)

__device__ __forceinline__ float gelu_tanh(float x) {
    const float c = 0.7978845608028654f;   // sqrt(2/pi)
    float t = tanhf(c * (x + 0.044715f * x * x * x));
    return 0.5f * x * (1.0f + t);
}

// ---------------------------------------------------------------------------
// fp32 -> bf16 cast (weights), 4 elements/thread
// ---------------------------------------------------------------------------
__global__ __launch_bounds__(256) void cast_bf16_kernel(
    const float* __restrict__ in, bf16_t* __restrict__ out)
{
    const int i = (blockIdx.x * 256 + threadIdx.x) * 4;
    const float4 v = *(const float4*)(in + i);
    bf16x4 o;
    o[0] = (bf16_t)v.x; o[1] = (bf16_t)v.y; o[2] = (bf16_t)v.z; o[3] = (bf16_t)v.w;
    *(bf16x4*)(out + i) = o;
}

// ---------------------------------------------------------------------------
// RMSNorm -> bf16 output: one block per row of 1024 floats
// ---------------------------------------------------------------------------
__global__ __launch_bounds__(256) void rmsnorm_bf16_kernel(
    const float* __restrict__ in, const float* __restrict__ w,
    bf16_t* __restrict__ out)
{
    const int row = blockIdx.x;
    const float4* ip = (const float4*)(in + (size_t)row * DD);
    float4 v = ip[threadIdx.x];
    float ss = v.x*v.x + v.y*v.y + v.z*v.z + v.w*v.w;
    #pragma unroll
    for (int off = 32; off > 0; off >>= 1) ss += __shfl_down(ss, off, 64);
    __shared__ float sums[4];
    const int wid = threadIdx.x >> 6;
    if ((threadIdx.x & 63) == 0) sums[wid] = ss;
    __syncthreads();
    const float tot = sums[0] + sums[1] + sums[2] + sums[3];
    const float scale = rsqrtf(tot * (1.0f / (float)DD) + 1e-8f);
    const float4 wv = ((const float4*)w)[threadIdx.x];
    bf16x4 o;
    o[0] = (bf16_t)(v.x * scale * wv.x);
    o[1] = (bf16_t)(v.y * scale * wv.y);
    o[2] = (bf16_t)(v.z * scale * wv.z);
    o[3] = (bf16_t)(v.w * scale * wv.w);
    *(bf16x4*)(out + (size_t)row * DD + threadIdx.x * 4) = o;
}

// ---------------------------------------------------------------------------
// bf16 MFMA GEMM: C(M,N) = epi(A(M,K) @ W(N,K)^T + bias) [+ res]
// m97 structure: 128x128 tile, BK=32, 256 thr (4 waves, 2x2), each wave 4x4
// 16x16x32 MFMA tiles, global_load_lds width=16 staging, ds_read_b128 frags.
// EPI: 0 = bias, 1 = bias + residual, 2 = bias + tanh-GELU
// ---------------------------------------------------------------------------
template<int EPI, bool BF16OUT>
__global__ __launch_bounds__(256) void gemm_mfma_kernel(
    const bf16_t* __restrict__ A,    // (M,K)
    const bf16_t* __restrict__ W,    // (N,K)
    const float* __restrict__ bias,  // (N)
    const float* __restrict__ res,   // (M,N) or nullptr
    float* __restrict__ Cf,          // fp32 out (if !BF16OUT)
    bf16_t* __restrict__ Cb,         // bf16 out (if BF16OUT)
    int M, int N, int K)
{
    __shared__ __align__(16) bf16_t As[128 * 32];
    __shared__ __align__(16) bf16_t Ws[128 * 32];
    const int tid  = threadIdx.x;
    const int bm   = blockIdx.y * 128;
    const int bn   = blockIdx.x * 128;
    const int lane = tid & 63;
    const int wave = tid >> 6;
    const int wr   = (wave >> 1) * 64;   // wave row offset within tile
    const int wc   = (wave & 1) * 64;    // wave col offset within tile

    // staging: thread t covers LDS bytes [t*16, t*16+16) of each 4KB half
    const int lrow = tid >> 2;           // 0..63
    const int lcol = (tid & 3) * 8;      // 0,8,16,24 (bf16 elements)

    const bf16_t* Ag = A + (size_t)(bm + lrow) * K + lcol;
    const bf16_t* Wg = W + (size_t)(bn + lrow) * K + lcol;
    bf16_t* AsL0 = As + lrow * 32 + lcol;
    bf16_t* AsL1 = As + (64 + lrow) * 32 + lcol;
    bf16_t* WsL0 = Ws + lrow * 32 + lcol;
    bf16_t* WsL1 = Ws + (64 + lrow) * 32 + lcol;

    f32x4 acc[4][4] = {};

    const int fr = lane & 15;            // m (or n) within 16-tile
    const int fc = (lane >> 4) * 8;      // k offset (quad*8)

    for (int k0 = 0; k0 < K; k0 += 32) {
        GLD_LDS16(Ag + k0,               AsL0);
        GLD_LDS16(Ag + (size_t)64*K + k0, AsL1);
        GLD_LDS16(Wg + k0,               WsL0);
        GLD_LDS16(Wg + (size_t)64*K + k0, WsL1);
        __syncthreads();

        bf16x8 af[4], wf[4];
        #pragma unroll
        for (int i = 0; i < 4; ++i)
            af[i] = *(const bf16x8*)(As + (wr + i*16 + fr) * 32 + fc);
        #pragma unroll
        for (int j = 0; j < 4; ++j)
            wf[j] = *(const bf16x8*)(Ws + (wc + j*16 + fr) * 32 + fc);
        #pragma unroll
        for (int i = 0; i < 4; ++i)
            #pragma unroll
            for (int j = 0; j < 4; ++j)
                acc[i][j] = __builtin_amdgcn_mfma_f32_16x16x32_bf16(
                    af[i], wf[j], acc[i][j], 0, 0, 0);
        __syncthreads();
    }

    // Epilogue. C/D layout: col = lane&15, row = (lane>>4)*4 + reg
    const int fq = lane >> 4;
    #pragma unroll
    for (int i = 0; i < 4; ++i) {
        const int row0 = bm + wr + i*16 + fq*4;
        #pragma unroll
        for (int j = 0; j < 4; ++j) {
            const int col = bn + wc + j*16 + fr;
            const float bcol = bias[col];
            #pragma unroll
            for (int r = 0; r < 4; ++r) {
                float v = acc[i][j][r] + bcol;
                if constexpr (EPI == 2) v = gelu_tanh(v);
                if constexpr (EPI == 1) v += res[(size_t)(row0 + r) * N + col];
                if constexpr (BF16OUT)
                    Cb[(size_t)(row0 + r) * N + col] = (bf16_t)v;
                else
                    Cf[(size_t)(row0 + r) * N + col] = v;
            }
        }
    }
}

// ---------------------------------------------------------------------------
// Depthwise causal k=3 short filter on u (B,L,3D), producing
//   x0  (B,L,D)   = conv channels [0,D)
//   vin (B,D,L)   = conv[2D..3D) * conv[D..2D)    (v * x1 gate)
// ---------------------------------------------------------------------------
__global__ __launch_bounds__(256) void shortfilter_kernel(
    const float* __restrict__ u, const float* __restrict__ sw,
    const float* __restrict__ sb, float* __restrict__ x0,
    float* __restrict__ vin)
{
    const int bl = blockIdx.x;          // b*L + l
    const int b = bl >> 11;
    const int l = bl & (LL - 1);
    const float* u0 = u + (size_t)bl * (3 * DD);
    #pragma unroll
    for (int i = 0; i < 4; ++i) {
        const int d = threadIdx.x + (i << 8);
        float vals[3];
        #pragma unroll
        for (int g = 0; g < 3; ++g) {
            const int c = (g << 10) + d;
            float acc = sw[c * 3 + 2] * u0[c] + sb[c];
            if (l >= 1) acc += sw[c * 3 + 1] * u0[c - 3 * DD];
            if (l >= 2) acc += sw[c * 3 + 0] * u0[c - 6 * DD];
            vals[g] = acc;
        }
        x0[(size_t)bl * DD + d] = vals[0];
        vin[((size_t)(b << 10) + d) * LL + l] = vals[2] * vals[1];
    }
}

// ---------------------------------------------------------------------------
// Implicit filter MLP -> kfilt (D,L). One block per position l.
// ---------------------------------------------------------------------------
__global__ __launch_bounds__(256) void filtergen_kernel(
    const float* __restrict__ w1, const float* __restrict__ b1,
    const float* __restrict__ f1, const float* __restrict__ w2,
    const float* __restrict__ b2, const float* __restrict__ f2,
    const float* __restrict__ w3, float* __restrict__ kfilt)
{
    __shared__ float h1[64];
    __shared__ float h2[64];
    const int l = blockIdx.x;
    const float t = (float)l / (float)(LL - 1);
    const float ang = 1e-4f * 6.283185307179586f * (float)l / (float)LL;
    const float z0 = t, z1 = cosf(ang), z2 = -sinf(ang);
    const int tid = threadIdx.x;
    if (tid < 64) {
        float s = w1[tid*3+0]*z0 + w1[tid*3+1]*z1 + w1[tid*3+2]*z2 + b1[tid];
        h1[tid] = sinf(f1[tid] * s);
    }
    __syncthreads();
    if (tid < 64) {
        float s = b2[tid];
        #pragma unroll 8
        for (int j = 0; j < 64; ++j) s += w2[tid*64+j] * h1[j];
        h2[tid] = sinf(f2[tid] * s);
    }
    __syncthreads();
    const float min_decay = -3.0701134573253944f;   // ln(1e-2)/1.5
    const float max_decay = -15.350567286626972f;   // ln(1e-2)/0.3
    #pragma unroll
    for (int i = 0; i < 4; ++i) {
        const int d = tid + (i << 8);
        float s = 0.f;
        #pragma unroll 8
        for (int j = 0; j < 64; ++j) s += w3[d*64+j] * h2[j];
        const float delta = fabsf(min_decay + (max_decay - min_decay) * (float)d / (float)(DD - 1));
        kfilt[(size_t)d * LL + l] = s * expf(-t * delta);
    }
}

// ---------------------------------------------------------------------------
// 4096-point complex Stockham radix-2 FFT in LDS (12 stages, autosort).
// sign = -1 forward, +1 unnormalized inverse. 256 threads, 8 butterflies each.
// ---------------------------------------------------------------------------
__device__ __forceinline__ int fft4096_stages(float2 (*bufs)[4096], int cur, float sign)
{
    int n = 4096;
    int ls = 0;                       // log2(stride)
    while (n > 1) {
        const int m = n >> 1;
        const float theta = sign * 6.283185307179586f / (float)n;
        float2* __restrict__ src = bufs[cur];
        float2* __restrict__ dst = bufs[cur ^ 1];
        const int s = 1 << ls;
        #pragma unroll
        for (int it = 0; it < 8; ++it) {
            const int idx = (int)threadIdx.x + (it << 8);   // 0..2047
            const int p = idx >> ls;
            const int q = idx & (s - 1);
            const float2 a = src[q + (p << ls)];
            const float2 b = src[q + ((p + m) << ls)];
            float sn, cs;
            __sincosf(theta * (float)p, &sn, &cs);
            const float rx = a.x - b.x, ry = a.y - b.y;
            dst[q + (p << (ls + 1))]     = make_float2(a.x + b.x, a.y + b.y);
            dst[q + (p << (ls + 1)) + s] = make_float2(rx * cs - ry * sn,
                                                       rx * sn + ry * cs);
        }
        __syncthreads();
        cur ^= 1;
        n = m;
        ++ls;
    }
    return cur;
}

// FFT of filter rows: Kf[d, 0..2048] = FFT_4096(k[d,:] zero-padded)/4096
// (only the non-redundant half; rest via conjugate symmetry)
__global__ __launch_bounds__(256) void kfft_kernel(
    const float* __restrict__ kfilt, float2* __restrict__ Kf)
{
    __shared__ float2 fb[2][4096];
    const int d = blockIdx.x;
    const float* kr = kfilt + (size_t)d * LL;
    const float inv = 1.0f / 4096.0f;
    for (int i = threadIdx.x; i < LL; i += 256) {
        fb[0][i]      = make_float2(kr[i] * inv, 0.f);
        fb[0][i + LL] = make_float2(0.f, 0.f);
    }
    __syncthreads();
    const int cur = fft4096_stages(fb, 0, -1.0f);
    float2* out = Kf + (size_t)d * KF_STRIDE;
    for (int i = threadIdx.x; i <= 2048; i += 256) out[i] = fb[cur][i];
}

// In-place causal long conv per (b,d) row: vio <- conv(vio, k) + bias*vio
__global__ __launch_bounds__(256) void fftconv_kernel(
    float* __restrict__ vio, const float2* __restrict__ Kf,
    const float* __restrict__ fbias)
{
    __shared__ float2 fb[2][4096];
    const int row = blockIdx.x;           // b*D + d
    const int d = row & (DD - 1);
    float* v = vio + (size_t)row * LL;
    for (int i = threadIdx.x; i < LL; i += 256) {
        fb[0][i]      = make_float2(v[i], 0.f);
        fb[0][i + LL] = make_float2(0.f, 0.f);
    }
    __syncthreads();
    int cur = fft4096_stages(fb, 0, -1.0f);
    const float2* kf = Kf + (size_t)d * KF_STRIDE;
    for (int i = threadIdx.x; i < 4096; i += 256) {
        const float2 a = fb[cur][i];
        float2 k;
        if (i <= 2048) k = kf[i];
        else { const float2 t = kf[4096 - i]; k = make_float2(t.x, -t.y); }
        fb[cur][i] = make_float2(a.x * k.x - a.y * k.y,
                                 a.x * k.y + a.y * k.x);
    }
    __syncthreads();
    cur = fft4096_stages(fb, cur, 1.0f);   // unnormalized inverse
    const float bias = fbias[d];
    for (int i = threadIdx.x; i < LL; i += 256) {
        v[i] = fb[cur][i].x + bias * v[i];
    }
}

// ---------------------------------------------------------------------------
// gated_bf16(B,L,D) = bf16( y(B,D,L) * x0(B,L,D) )  -- LDS 32x32 transpose
// ---------------------------------------------------------------------------
__global__ __launch_bounds__(256) void gate_transpose_kernel(
    const float* __restrict__ y, const float* __restrict__ x0,
    bf16_t* __restrict__ g)
{
    __shared__ float tile[32][33];
    const int b  = blockIdx.z;
    const int l0 = blockIdx.x * 32;
    const int d0 = blockIdx.y * 32;
    const int tx  = threadIdx.x & 31;
    const int tyb = threadIdx.x >> 5;    // 0..7
    #pragma unroll
    for (int i = 0; i < 4; ++i) {
        const int dy = tyb + i * 8;
        tile[dy][tx] = y[((size_t)(b * DD + d0 + dy)) * LL + l0 + tx];
    }
    __syncthreads();
    #pragma unroll
    for (int i = 0; i < 4; ++i) {
        const int ly = tyb + i * 8;
        const size_t idx = ((size_t)(b * LL + l0 + ly)) * DD + d0 + tx;
        g[idx] = (bf16_t)(tile[tx][ly] * x0[idx]);
    }
}

// ---------------------------------------------------------------------------
// Launch
// ---------------------------------------------------------------------------
extern "C" void kernel_launch(void* const* d_in, const int* in_sizes, int n_in,
                              void* d_out, int out_size, void* d_ws, size_t ws_size,
                              hipStream_t stream)
{
    (void)in_sizes; (void)n_in; (void)out_size; (void)ws_size;
    const float* x   = (const float*)d_in[0];
    const float* nw0 = (const float*)d_in[1];
    const float* ipw = (const float*)d_in[2];
    const float* ipb = (const float*)d_in[3];
    const float* sfw = (const float*)d_in[4];
    const float* sfb = (const float*)d_in[5];
    const float* w1  = (const float*)d_in[6];
    const float* b1  = (const float*)d_in[7];
    const float* f1  = (const float*)d_in[8];
    const float* w2  = (const float*)d_in[9];
    const float* b2  = (const float*)d_in[10];
    const float* f2  = (const float*)d_in[11];
    const float* w3  = (const float*)d_in[12];
    const float* fbv = (const float*)d_in[13];
    const float* opw = (const float*)d_in[14];
    const float* opb = (const float*)d_in[15];
    const float* nw1 = (const float*)d_in[16];
    const float* fw1 = (const float*)d_in[17];
    const float* fb1 = (const float*)d_in[18];
    const float* fw2 = (const float*)d_in[19];
    const float* fb2 = (const float*)d_in[20];
    float* out = (float*)d_out;

    float* ws = (float*)d_ws;
    // Region 0: u (B,L,3D) fp32 = 25,165,824 f. After shortfilter consumes u,
    // the same region holds: gated_bf16 (8M bf16), h (8M f), mid_bf16 (16M bf16).
    float*  u      = ws;
    bf16_t* gatedb = (bf16_t*)ws;                       // 8,388,608 bf16 (4,194,304 f)
    float*  h      = ws + 4194304;                      // 8,388,608 f
    bf16_t* midb   = (bf16_t*)(ws + 12582912);          // 16,777,216 bf16 (8,388,608 f)
    bf16_t* xnb    = (bf16_t*)(ws + 25165824);          // 8M bf16 (also hn later)
    float*  x0     = ws + 29360128;                     // 8,388,608 f
    float*  vio    = ws + 37748736;                     // 8,388,608 f (vin -> y)
    float*  kfilt  = ws + 46137344;                     // 2,097,152 f
    float2* Kf     = (float2*)(ws + 48234496);          // 1024 x KF_STRIDE cplx
    bf16_t* ipwb   = (bf16_t*)(ws + 52445184);          // 3,145,728 bf16
    bf16_t* opwb   = ipwb + 3145728;                    // 1,048,576 bf16
    bf16_t* fw1b   = opwb + 1048576;                    // 2,097,152 bf16
    bf16_t* fw2b   = fw1b + 2097152;                    // 2,097,152 bf16
    // total: 56,639,488 f = 226.6 MB

    // 0. weight casts
    cast_bf16_kernel<<<3072*1024/1024, 256, 0, stream>>>(ipw, ipwb);
    cast_bf16_kernel<<<1024*1024/1024, 256, 0, stream>>>(opw, opwb);
    cast_bf16_kernel<<<2048*1024/1024, 256, 0, stream>>>(fw1, fw1b);
    cast_bf16_kernel<<<2048*1024/1024, 256, 0, stream>>>(fw2, fw2b);
    // 1. implicit filter -> kfilt (D,L);  Kf = FFT(kfilt)/4096 (half spectrum)
    filtergen_kernel<<<LL, 256, 0, stream>>>(w1, b1, f1, w2, b2, f2, w3, kfilt);
    kfft_kernel<<<DD, 256, 0, stream>>>(kfilt, Kf);
    // 2. xn = bf16(rmsnorm(x, norm_in_w))
    rmsnorm_bf16_kernel<<<MM, 256, 0, stream>>>(x, nw0, xnb);
    // 3. u = xn @ in_proj_w^T + b           (M=8192, N=3072, K=1024)
    gemm_mfma_kernel<0, false><<<dim3(3072/128, MM/128), 256, 0, stream>>>(
        xnb, ipwb, ipb, nullptr, u, nullptr, MM, 3*DD, DD);
    // 4. short filter -> x0 (B,L,D), vin (B,D,L)
    shortfilter_kernel<<<MM, 256, 0, stream>>>(u, sfw, sfb, x0, vio);
    // 5. vio <- causal_conv(vio, k) + filter_bias * vio   (in place)
    fftconv_kernel<<<BB*DD, 256, 0, stream>>>(vio, Kf, fbv);
    // 6. gated_bf16(B,L,D) = y * x0
    gate_transpose_kernel<<<dim3(LL/32, DD/32, BB), 256, 0, stream>>>(vio, x0, gatedb);
    // 7. h = gated @ out_proj_w^T + b + x   (M=8192, N=1024, K=1024)
    gemm_mfma_kernel<1, false><<<dim3(DD/128, MM/128), 256, 0, stream>>>(
        gatedb, opwb, opb, x, h, nullptr, MM, DD, DD);
    // 8. hn = bf16(rmsnorm(h, norm_w))
    rmsnorm_bf16_kernel<<<MM, 256, 0, stream>>>(h, nw1, xnb);
    // 9. mid = bf16(gelu(hn @ ffn_w1^T + b))  (M=8192, N=2048, K=1024)
    gemm_mfma_kernel<2, true><<<dim3(2*DD/128, MM/128), 256, 0, stream>>>(
        xnb, fw1b, fb1, nullptr, nullptr, midb, MM, 2*DD, DD);
    // 10. out = mid @ ffn_w2^T + b + h      (M=8192, N=1024, K=2048)
    gemm_mfma_kernel<1, false><<<dim3(DD/128, MM/128), 256, 0, stream>>>(
        midb, fw2b, fb2, h, out, nullptr, MM, DD, 2*DD);
}

// Round 3
// 695.047 us; speedup vs baseline: 3.4088x; 1.2868x over previous
//
#include <hip/hip_runtime.h>
#include <hip/hip_bf16.h>
#include <cstddef>

// ---------------------------------------------------------------------------
// Constants for this problem: B=4, L=2048, D=1024
// ---------------------------------------------------------------------------
#define BB 4
#define LL 2048
#define DD 1024
#define MM (BB*LL)          // 8192 tokens
#define KF_STRIDE 2056      // complex elements per Kf row (>= 2049, 16B-aligned)

// LDS bank swizzle for float2 arrays: makes all Stockham read/write streams
// uniform across the 16 bank-pairs. Modifies bits 2-3 only (stays in range).
#define SWZ(a) ((a) ^ (((a) >> 4) & 12))

typedef __bf16 bf16_t;
typedef __attribute__((ext_vector_type(8))) __bf16 bf16x8;
typedef __attribute__((ext_vector_type(4))) __bf16 bf16x4;
typedef __attribute__((ext_vector_type(4))) float f32x4;

// async global->LDS, 16 bytes per lane (global_load_lds_dwordx4)
#define GLD_LDS16(gp, lp) __builtin_amdgcn_global_load_lds(                 \
    (const __attribute__((address_space(1))) unsigned int*)(gp),            \
    (__attribute__((address_space(3))) unsigned int*)(lp), 16, 0, 0)

__device__ __forceinline__ float gelu_tanh(float x) {
    const float c = 0.7978845608028654f;   // sqrt(2/pi)
    float t = tanhf(c * (x + 0.044715f * x * x * x));
    return 0.5f * x * (1.0f + t);
}

__device__ __forceinline__ float2 cmul(float2 a, float2 b) {
    return make_float2(a.x * b.x - a.y * b.y, a.x * b.y + a.y * b.x);
}

// ---------------------------------------------------------------------------
// fp32 -> bf16 cast (weights), 4 elements/thread
// ---------------------------------------------------------------------------
__global__ __launch_bounds__(256) void cast_bf16_kernel(
    const float* __restrict__ in, bf16_t* __restrict__ out)
{
    const int i = (blockIdx.x * 256 + threadIdx.x) * 4;
    const float4 v = *(const float4*)(in + i);
    bf16x4 o;
    o[0] = (bf16_t)v.x; o[1] = (bf16_t)v.y; o[2] = (bf16_t)v.z; o[3] = (bf16_t)v.w;
    *(bf16x4*)(out + i) = o;
}

// ---------------------------------------------------------------------------
// RMSNorm -> bf16 output: one block per row of 1024 floats
// ---------------------------------------------------------------------------
__global__ __launch_bounds__(256) void rmsnorm_bf16_kernel(
    const float* __restrict__ in, const float* __restrict__ w,
    bf16_t* __restrict__ out)
{
    const int row = blockIdx.x;
    const float4* ip = (const float4*)(in + (size_t)row * DD);
    float4 v = ip[threadIdx.x];
    float ss = v.x*v.x + v.y*v.y + v.z*v.z + v.w*v.w;
    #pragma unroll
    for (int off = 32; off > 0; off >>= 1) ss += __shfl_down(ss, off, 64);
    __shared__ float sums[4];
    const int wid = threadIdx.x >> 6;
    if ((threadIdx.x & 63) == 0) sums[wid] = ss;
    __syncthreads();
    const float tot = sums[0] + sums[1] + sums[2] + sums[3];
    const float scale = rsqrtf(tot * (1.0f / (float)DD) + 1e-8f);
    const float4 wv = ((const float4*)w)[threadIdx.x];
    bf16x4 o;
    o[0] = (bf16_t)(v.x * scale * wv.x);
    o[1] = (bf16_t)(v.y * scale * wv.y);
    o[2] = (bf16_t)(v.z * scale * wv.z);
    o[3] = (bf16_t)(v.w * scale * wv.w);
    *(bf16x4*)(out + (size_t)row * DD + threadIdx.x * 4) = o;
}

// ---------------------------------------------------------------------------
// bf16 MFMA GEMM: C(M,N) = epi(A(M,K) @ W(N,K)^T + bias) [+ res]
// 128x128 tile, BK=32, 256 thr (4 waves, 2x2), each wave 4x4 16x16x32 MFMA
// tiles, global_load_lds width=16 staging, ds_read_b128 fragments.
// EPI: 0 = bias, 1 = bias + residual, 2 = bias + tanh-GELU
// ---------------------------------------------------------------------------
template<int EPI, bool BF16OUT>
__global__ __launch_bounds__(256) void gemm_mfma_kernel(
    const bf16_t* __restrict__ A,    // (M,K)
    const bf16_t* __restrict__ W,    // (N,K)
    const float* __restrict__ bias,  // (N)
    const float* __restrict__ res,   // (M,N) or nullptr
    float* __restrict__ Cf,          // fp32 out (if !BF16OUT)
    bf16_t* __restrict__ Cb,         // bf16 out (if BF16OUT)
    int M, int N, int K)
{
    __shared__ __align__(16) bf16_t As[128 * 32];
    __shared__ __align__(16) bf16_t Ws[128 * 32];
    const int tid  = threadIdx.x;
    const int bm   = blockIdx.y * 128;
    const int bn   = blockIdx.x * 128;
    const int lane = tid & 63;
    const int wave = tid >> 6;
    const int wr   = (wave >> 1) * 64;   // wave row offset within tile
    const int wc   = (wave & 1) * 64;    // wave col offset within tile

    const int lrow = tid >> 2;           // 0..63
    const int lcol = (tid & 3) * 8;      // 0,8,16,24 (bf16 elements)

    const bf16_t* Ag = A + (size_t)(bm + lrow) * K + lcol;
    const bf16_t* Wg = W + (size_t)(bn + lrow) * K + lcol;
    bf16_t* AsL0 = As + lrow * 32 + lcol;
    bf16_t* AsL1 = As + (64 + lrow) * 32 + lcol;
    bf16_t* WsL0 = Ws + lrow * 32 + lcol;
    bf16_t* WsL1 = Ws + (64 + lrow) * 32 + lcol;

    f32x4 acc[4][4] = {};

    const int fr = lane & 15;            // m (or n) within 16-tile
    const int fc = (lane >> 4) * 8;      // k offset (quad*8)

    for (int k0 = 0; k0 < K; k0 += 32) {
        GLD_LDS16(Ag + k0,                AsL0);
        GLD_LDS16(Ag + (size_t)64*K + k0, AsL1);
        GLD_LDS16(Wg + k0,                WsL0);
        GLD_LDS16(Wg + (size_t)64*K + k0, WsL1);
        __syncthreads();

        bf16x8 af[4], wf[4];
        #pragma unroll
        for (int i = 0; i < 4; ++i)
            af[i] = *(const bf16x8*)(As + (wr + i*16 + fr) * 32 + fc);
        #pragma unroll
        for (int j = 0; j < 4; ++j)
            wf[j] = *(const bf16x8*)(Ws + (wc + j*16 + fr) * 32 + fc);
        #pragma unroll
        for (int i = 0; i < 4; ++i)
            #pragma unroll
            for (int j = 0; j < 4; ++j)
                acc[i][j] = __builtin_amdgcn_mfma_f32_16x16x32_bf16(
                    af[i], wf[j], acc[i][j], 0, 0, 0);
        __syncthreads();
    }

    // Epilogue. C/D layout: col = lane&15, row = (lane>>4)*4 + reg
    const int fq = lane >> 4;
    #pragma unroll
    for (int i = 0; i < 4; ++i) {
        const int row0 = bm + wr + i*16 + fq*4;
        #pragma unroll
        for (int j = 0; j < 4; ++j) {
            const int col = bn + wc + j*16 + fr;
            const float bcol = bias[col];
            #pragma unroll
            for (int r = 0; r < 4; ++r) {
                float v = acc[i][j][r] + bcol;
                if constexpr (EPI == 2) v = gelu_tanh(v);
                if constexpr (EPI == 1) v += res[(size_t)(row0 + r) * N + col];
                if constexpr (BF16OUT)
                    Cb[(size_t)(row0 + r) * N + col] = (bf16_t)v;
                else
                    Cf[(size_t)(row0 + r) * N + col] = v;
            }
        }
    }
}

// ---------------------------------------------------------------------------
// Depthwise causal k=3 short filter on u (B,L,3D), producing
//   x0  (B,L,D)   = conv channels [0,D)
//   vin (B,D,L)   = conv[2D..3D) * conv[D..2D)    (v * x1 gate)
// ---------------------------------------------------------------------------
__global__ __launch_bounds__(256) void shortfilter_kernel(
    const float* __restrict__ u, const float* __restrict__ sw,
    const float* __restrict__ sb, float* __restrict__ x0,
    float* __restrict__ vin)
{
    const int bl = blockIdx.x;          // b*L + l
    const int b = bl >> 11;
    const int l = bl & (LL - 1);
    const float* u0 = u + (size_t)bl * (3 * DD);
    #pragma unroll
    for (int i = 0; i < 4; ++i) {
        const int d = threadIdx.x + (i << 8);
        float vals[3];
        #pragma unroll
        for (int g = 0; g < 3; ++g) {
            const int c = (g << 10) + d;
            float acc = sw[c * 3 + 2] * u0[c] + sb[c];
            if (l >= 1) acc += sw[c * 3 + 1] * u0[c - 3 * DD];
            if (l >= 2) acc += sw[c * 3 + 0] * u0[c - 6 * DD];
            vals[g] = acc;
        }
        x0[(size_t)bl * DD + d] = vals[0];
        vin[((size_t)(b << 10) + d) * LL + l] = vals[2] * vals[1];
    }
}

// ---------------------------------------------------------------------------
// Implicit filter MLP -> kfilt (D,L). One block per position l.
// ---------------------------------------------------------------------------
__global__ __launch_bounds__(256) void filtergen_kernel(
    const float* __restrict__ w1, const float* __restrict__ b1,
    const float* __restrict__ f1, const float* __restrict__ w2,
    const float* __restrict__ b2, const float* __restrict__ f2,
    const float* __restrict__ w3, float* __restrict__ kfilt)
{
    __shared__ float h1[64];
    __shared__ float h2[64];
    const int l = blockIdx.x;
    const float t = (float)l / (float)(LL - 1);
    const float ang = 1e-4f * 6.283185307179586f * (float)l / (float)LL;
    const float z0 = t, z1 = cosf(ang), z2 = -sinf(ang);
    const int tid = threadIdx.x;
    if (tid < 64) {
        float s = w1[tid*3+0]*z0 + w1[tid*3+1]*z1 + w1[tid*3+2]*z2 + b1[tid];
        h1[tid] = sinf(f1[tid] * s);
    }
    __syncthreads();
    if (tid < 64) {
        float s = b2[tid];
        #pragma unroll 8
        for (int j = 0; j < 64; ++j) s += w2[tid*64+j] * h1[j];
        h2[tid] = sinf(f2[tid] * s);
    }
    __syncthreads();
    const float min_decay = -3.0701134573253944f;   // ln(1e-2)/1.5
    const float max_decay = -15.350567286626972f;   // ln(1e-2)/0.3
    #pragma unroll
    for (int i = 0; i < 4; ++i) {
        const int d = tid + (i << 8);
        float s = 0.f;
        #pragma unroll 8
        for (int j = 0; j < 64; ++j) s += w3[d*64+j] * h2[j];
        const float delta = fabsf(min_decay + (max_decay - min_decay) * (float)d / (float)(DD - 1));
        kfilt[(size_t)d * LL + l] = s * expf(-t * delta);
    }
}

// ---------------------------------------------------------------------------
// 4096-point complex Stockham radix-4 FFT in LDS (6 stages, autosort).
// Derived by fusing pairs of the (verified) radix-2 Stockham stages.
// SIGN = -1 forward, +1 unnormalized inverse. NT threads, 1024/NT
// butterflies each. All LDS indices pass through SWZ (bank uniformity).
// ---------------------------------------------------------------------------
template<int NT, int SIGN>
__device__ __forceinline__ int fft4096_r4(float2 (*bufs)[4096], int cur)
{
    constexpr int NB = 1024 / NT;
    const float fsign = (float)SIGN;
    #pragma unroll
    for (int t = 0; t < 6; ++t) {
        const int ls = 2 * t;                        // log2(stride)
        const float theta = fsign * 6.283185307179586f / (float)(4096 >> ls);
        float2* __restrict__ src = bufs[cur];
        float2* __restrict__ dst = bufs[cur ^ 1];
        #pragma unroll
        for (int it = 0; it < NB; ++it) {
            const int idx = (int)threadIdx.x + it * NT;   // 0..1023
            const int p = idx >> ls;
            const int q = idx & ((1 << ls) - 1);
            const float2 a0 = src[SWZ(idx)];
            const float2 a1 = src[SWZ(idx + 1024)];
            const float2 a2 = src[SWZ(idx + 2048)];
            const float2 a3 = src[SWZ(idx + 3072)];
            float sn, cs;
            __sincosf(theta * (float)p, &sn, &cs);
            const float2 W  = make_float2(cs, sn);
            const float2 W2 = make_float2(cs*cs - sn*sn, 2.0f*cs*sn);
            const float2 u0 = make_float2(a0.x + a2.x, a0.y + a2.y);
            const float2 u1 = make_float2(a1.x + a3.x, a1.y + a3.y);
            const float2 t2 = make_float2(a0.x - a2.x, a0.y - a2.y);
            const float2 t3 = make_float2(a1.x - a3.x, a1.y - a3.y);
            const float2 u2 = cmul(W, t2);
            // u3 = W * (i*SIGN) * t3
            const float2 it3 = make_float2(-fsign * t3.y, fsign * t3.x);
            const float2 u3 = cmul(W, it3);
            const int o = q + (p << (ls + 2));
            dst[SWZ(o)]             = make_float2(u0.x + u1.x, u0.y + u1.y);
            dst[SWZ(o + (1 << ls))] = make_float2(u2.x + u3.x, u2.y + u3.y);
            dst[SWZ(o + (2 << ls))] = cmul(make_float2(u0.x - u1.x, u0.y - u1.y), W2);
            dst[SWZ(o + (3 << ls))] = cmul(make_float2(u2.x - u3.x, u2.y - u3.y), W2);
        }
        __syncthreads();
        cur ^= 1;
    }
    return cur;
}

// ---------------------------------------------------------------------------
// FFT of filter rows, two real rows per block (z = k_{2d} + i*k_{2d+1}).
// Half-spectra extracted via conjugate symmetry; /4096 folded in.
// ---------------------------------------------------------------------------
__global__ __launch_bounds__(512) void kfft_kernel(
    const float* __restrict__ kfilt, float2* __restrict__ Kf)
{
    __shared__ float2 fb[2][4096];
    const int d0 = blockIdx.x * 2;
    const float* k0 = kfilt + (size_t)d0 * LL;
    const float* k1 = k0 + LL;
    const float inv = 1.0f / 4096.0f;
    const int tid = threadIdx.x;
    for (int i = tid; i < 2048; i += 512) {
        fb[0][SWZ(i)]        = make_float2(k0[i] * inv, k1[i] * inv);
        fb[0][SWZ(i + 2048)] = make_float2(0.f, 0.f);
    }
    __syncthreads();
    const int cur = fft4096_r4<512, -1>(fb, 0);
    float2* o0 = Kf + (size_t)d0 * KF_STRIDE;
    float2* o1 = o0 + KF_STRIDE;
    for (int k = tid; k <= 2048; k += 512) {
        const float2 z1 = fb[cur][SWZ(k)];
        const float2 z2 = fb[cur][SWZ((4096 - k) & 4095)];
        // K_{2d}[k]   = (Z[k] + conj(Z[N-k]))/2
        o0[k] = make_float2(0.5f * (z1.x + z2.x), 0.5f * (z1.y - z2.y));
        // K_{2d+1}[k] = -i*(Z[k] - conj(Z[N-k]))/2
        o1[k] = make_float2(0.5f * (z1.y + z2.y), 0.5f * (z2.x - z1.x));
    }
}

// ---------------------------------------------------------------------------
// Long conv, two real rows per block: z = v1 + i*v2, filter k is REAL, so
// conv(v1,k) = Re(IFFT(Z*K)), conv(v2,k) = Im(IFFT(Z*K)). In place + bias.
// Rows paired as (2b*D+d, (2b+1)*D+d) -> same Kf[d].
// ---------------------------------------------------------------------------
__global__ __launch_bounds__(512) void fftconv_kernel(
    float* __restrict__ vio, const float2* __restrict__ Kf,
    const float* __restrict__ fbias)
{
    __shared__ float2 fb[2][4096];
    const int blk = blockIdx.x;          // [0, 2048)
    const int b2  = blk >> 10;           // 0..1
    const int d   = blk & (DD - 1);
    float* v1 = vio + ((size_t)(b2 * 2) * DD + d) * LL;
    float* v2 = v1 + (size_t)DD * LL;
    const int tid = threadIdx.x;
    for (int i = tid; i < 2048; i += 512) {
        fb[0][SWZ(i)]        = make_float2(v1[i], v2[i]);
        fb[0][SWZ(i + 2048)] = make_float2(0.f, 0.f);
    }
    __syncthreads();
    int cur = fft4096_r4<512, -1>(fb, 0);
    const float2* kf = Kf + (size_t)d * KF_STRIDE;
    for (int i = tid; i < 4096; i += 512) {
        const float2 a = fb[cur][SWZ(i)];
        float2 k;
        if (i <= 2048) k = kf[i];
        else { const float2 t = kf[4096 - i]; k = make_float2(t.x, -t.y); }
        fb[cur][SWZ(i)] = cmul(a, k);
    }
    __syncthreads();
    cur = fft4096_r4<512, 1>(fb, cur);
    const float bias = fbias[d];
    for (int i = tid; i < 2048; i += 512) {
        const float2 zy = fb[cur][SWZ(i)];
        v1[i] = zy.x + bias * v1[i];
        v2[i] = zy.y + bias * v2[i];
    }
}

// ---------------------------------------------------------------------------
// gated_bf16(B,L,D) = bf16( y(B,D,L) * x0(B,L,D) )  -- LDS 32x32 transpose
// ---------------------------------------------------------------------------
__global__ __launch_bounds__(256) void gate_transpose_kernel(
    const float* __restrict__ y, const float* __restrict__ x0,
    bf16_t* __restrict__ g)
{
    __shared__ float tile[32][33];
    const int b  = blockIdx.z;
    const int l0 = blockIdx.x * 32;
    const int d0 = blockIdx.y * 32;
    const int tx  = threadIdx.x & 31;
    const int tyb = threadIdx.x >> 5;    // 0..7
    #pragma unroll
    for (int i = 0; i < 4; ++i) {
        const int dy = tyb + i * 8;
        tile[dy][tx] = y[((size_t)(b * DD + d0 + dy)) * LL + l0 + tx];
    }
    __syncthreads();
    #pragma unroll
    for (int i = 0; i < 4; ++i) {
        const int ly = tyb + i * 8;
        const size_t idx = ((size_t)(b * LL + l0 + ly)) * DD + d0 + tx;
        g[idx] = (bf16_t)(tile[tx][ly] * x0[idx]);
    }
}

// ---------------------------------------------------------------------------
// Launch
// ---------------------------------------------------------------------------
extern "C" void kernel_launch(void* const* d_in, const int* in_sizes, int n_in,
                              void* d_out, int out_size, void* d_ws, size_t ws_size,
                              hipStream_t stream)
{
    (void)in_sizes; (void)n_in; (void)out_size; (void)ws_size;
    const float* x   = (const float*)d_in[0];
    const float* nw0 = (const float*)d_in[1];
    const float* ipw = (const float*)d_in[2];
    const float* ipb = (const float*)d_in[3];
    const float* sfw = (const float*)d_in[4];
    const float* sfb = (const float*)d_in[5];
    const float* w1  = (const float*)d_in[6];
    const float* b1  = (const float*)d_in[7];
    const float* f1  = (const float*)d_in[8];
    const float* w2  = (const float*)d_in[9];
    const float* b2  = (const float*)d_in[10];
    const float* f2  = (const float*)d_in[11];
    const float* w3  = (const float*)d_in[12];
    const float* fbv = (const float*)d_in[13];
    const float* opw = (const float*)d_in[14];
    const float* opb = (const float*)d_in[15];
    const float* nw1 = (const float*)d_in[16];
    const float* fw1 = (const float*)d_in[17];
    const float* fb1 = (const float*)d_in[18];
    const float* fw2 = (const float*)d_in[19];
    const float* fb2 = (const float*)d_in[20];
    float* out = (float*)d_out;

    float* ws = (float*)d_ws;
    // Region 0: u (B,L,3D) fp32 = 25,165,824 f. After shortfilter consumes u,
    // the same region holds: gated_bf16 (8M bf16), h (8M f), mid_bf16 (16M bf16).
    float*  u      = ws;
    bf16_t* gatedb = (bf16_t*)ws;                       // 8,388,608 bf16 (4,194,304 f)
    float*  h      = ws + 4194304;                      // 8,388,608 f
    bf16_t* midb   = (bf16_t*)(ws + 12582912);          // 16,777,216 bf16 (8,388,608 f)
    bf16_t* xnb    = (bf16_t*)(ws + 25165824);          // 8M bf16 (also hn later)
    float*  x0     = ws + 29360128;                     // 8,388,608 f
    float*  vio    = ws + 37748736;                     // 8,388,608 f (vin -> y)
    float*  kfilt  = ws + 46137344;                     // 2,097,152 f
    float2* Kf     = (float2*)(ws + 48234496);          // 1024 x KF_STRIDE cplx
    bf16_t* ipwb   = (bf16_t*)(ws + 52445184);          // 3,145,728 bf16
    bf16_t* opwb   = ipwb + 3145728;                    // 1,048,576 bf16
    bf16_t* fw1b   = opwb + 1048576;                    // 2,097,152 bf16
    bf16_t* fw2b   = fw1b + 2097152;                    // 2,097,152 bf16
    // total: 56,639,488 f = 226.6 MB

    // 0. weight casts
    cast_bf16_kernel<<<3072*1024/1024, 256, 0, stream>>>(ipw, ipwb);
    cast_bf16_kernel<<<1024*1024/1024, 256, 0, stream>>>(opw, opwb);
    cast_bf16_kernel<<<2048*1024/1024, 256, 0, stream>>>(fw1, fw1b);
    cast_bf16_kernel<<<2048*1024/1024, 256, 0, stream>>>(fw2, fw2b);
    // 1. implicit filter -> kfilt (D,L);  Kf = FFT(kfilt)/4096 (half spectrum)
    filtergen_kernel<<<LL, 256, 0, stream>>>(w1, b1, f1, w2, b2, f2, w3, kfilt);
    kfft_kernel<<<DD/2, 512, 0, stream>>>(kfilt, Kf);
    // 2. xn = bf16(rmsnorm(x, norm_in_w))
    rmsnorm_bf16_kernel<<<MM, 256, 0, stream>>>(x, nw0, xnb);
    // 3. u = xn @ in_proj_w^T + b           (M=8192, N=3072, K=1024)
    gemm_mfma_kernel<0, false><<<dim3(3072/128, MM/128), 256, 0, stream>>>(
        xnb, ipwb, ipb, nullptr, u, nullptr, MM, 3*DD, DD);
    // 4. short filter -> x0 (B,L,D), vin (B,D,L)
    shortfilter_kernel<<<MM, 256, 0, stream>>>(u, sfw, sfb, x0, vio);
    // 5. vio <- causal_conv(vio, k) + filter_bias * vio   (2 rows per block)
    fftconv_kernel<<<BB*DD/2, 512, 0, stream>>>(vio, Kf, fbv);
    // 6. gated_bf16(B,L,D) = y * x0
    gate_transpose_kernel<<<dim3(LL/32, DD/32, BB), 256, 0, stream>>>(vio, x0, gatedb);
    // 7. h = gated @ out_proj_w^T + b + x   (M=8192, N=1024, K=1024)
    gemm_mfma_kernel<1, false><<<dim3(DD/128, MM/128), 256, 0, stream>>>(
        gatedb, opwb, opb, x, h, nullptr, MM, DD, DD);
    // 8. hn = bf16(rmsnorm(h, norm_w))
    rmsnorm_bf16_kernel<<<MM, 256, 0, stream>>>(h, nw1, xnb);
    // 9. mid = bf16(gelu(hn @ ffn_w1^T + b))  (M=8192, N=2048, K=1024)
    gemm_mfma_kernel<2, true><<<dim3(2*DD/128, MM/128), 256, 0, stream>>>(
        xnb, fw1b, fb1, nullptr, nullptr, midb, MM, 2*DD, DD);
    // 10. out = mid @ ffn_w2^T + b + h      (M=8192, N=1024, K=2048)
    gemm_mfma_kernel<1, false><<<dim3(DD/128, MM/128), 256, 0, stream>>>(
        midb, fw2b, fb2, h, out, nullptr, MM, DD, 2*DD);
}

// Round 4
// 612.928 us; speedup vs baseline: 3.8655x; 1.1340x over previous
//
#include <hip/hip_runtime.h>
#include <hip/hip_bf16.h>
#include <cstddef>

// ---------------------------------------------------------------------------
// Constants for this problem: B=4, L=2048, D=1024
// ---------------------------------------------------------------------------
#define BB 4
#define LL 2048
#define DD 1024
#define MM (BB*LL)          // 8192 tokens
#define KF_STRIDE 2056      // complex elements per Kf row (>= 2049, 16B-aligned)

// LDS bank swizzle for float2 arrays: makes all Stockham read/write streams
// uniform across the 16 bank-pairs. Modifies bits 2-3 only (stays in range).
#define SWZ(a) ((a) ^ (((a) >> 4) & 12))

typedef __bf16 bf16_t;
typedef __attribute__((ext_vector_type(8))) __bf16 bf16x8;
typedef __attribute__((ext_vector_type(4))) __bf16 bf16x4;
typedef __attribute__((ext_vector_type(4))) float f32x4;

// async global->LDS, 16 bytes per lane (global_load_lds_dwordx4)
#define GLD_LDS16(gp, lp) __builtin_amdgcn_global_load_lds(                 \
    (const __attribute__((address_space(1))) unsigned int*)(gp),            \
    (__attribute__((address_space(3))) unsigned int*)(lp), 16, 0, 0)

__device__ __forceinline__ float gelu_tanh(float x) {
    const float c = 0.7978845608028654f;   // sqrt(2/pi)
    float t = tanhf(c * (x + 0.044715f * x * x * x));
    return 0.5f * x * (1.0f + t);
}

__device__ __forceinline__ float2 cmul(float2 a, float2 b) {
    return make_float2(a.x * b.x - a.y * b.y, a.x * b.y + a.y * b.x);
}

// ---------------------------------------------------------------------------
// fp32 -> bf16 cast (weights), 4 elements/thread
// ---------------------------------------------------------------------------
__global__ __launch_bounds__(256) void cast_bf16_kernel(
    const float* __restrict__ in, bf16_t* __restrict__ out)
{
    const int i = (blockIdx.x * 256 + threadIdx.x) * 4;
    const float4 v = *(const float4*)(in + i);
    bf16x4 o;
    o[0] = (bf16_t)v.x; o[1] = (bf16_t)v.y; o[2] = (bf16_t)v.z; o[3] = (bf16_t)v.w;
    *(bf16x4*)(out + i) = o;
}

// ---------------------------------------------------------------------------
// RMSNorm -> bf16 output: one block per row of 1024 floats
// ---------------------------------------------------------------------------
__global__ __launch_bounds__(256) void rmsnorm_bf16_kernel(
    const float* __restrict__ in, const float* __restrict__ w,
    bf16_t* __restrict__ out)
{
    const int row = blockIdx.x;
    const float4* ip = (const float4*)(in + (size_t)row * DD);
    float4 v = ip[threadIdx.x];
    float ss = v.x*v.x + v.y*v.y + v.z*v.z + v.w*v.w;
    #pragma unroll
    for (int off = 32; off > 0; off >>= 1) ss += __shfl_down(ss, off, 64);
    __shared__ float sums[4];
    const int wid = threadIdx.x >> 6;
    if ((threadIdx.x & 63) == 0) sums[wid] = ss;
    __syncthreads();
    const float tot = sums[0] + sums[1] + sums[2] + sums[3];
    const float scale = rsqrtf(tot * (1.0f / (float)DD) + 1e-8f);
    const float4 wv = ((const float4*)w)[threadIdx.x];
    bf16x4 o;
    o[0] = (bf16_t)(v.x * scale * wv.x);
    o[1] = (bf16_t)(v.y * scale * wv.y);
    o[2] = (bf16_t)(v.z * scale * wv.z);
    o[3] = (bf16_t)(v.w * scale * wv.w);
    *(bf16x4*)(out + (size_t)row * DD + threadIdx.x * 4) = o;
}

// ---------------------------------------------------------------------------
// bf16 MFMA GEMM: C(M,N) = epi(A(M,K) @ W(N,K)^T + bias) [+ res]
// 128x128 tile, BK=32, 256 thr (4 waves, 2x2), each wave 4x4 16x16x32 MFMA
// tiles, global_load_lds width=16 staging, ds_read_b128 fragments.
// EPI: 0 = bias, 1 = bias + residual, 2 = bias + tanh-GELU
// BIASROW: bias indexed by output row (for transposed-output GEMMs)
// ---------------------------------------------------------------------------
template<int EPI, bool BF16OUT, bool BIASROW = false>
__global__ __launch_bounds__(256) void gemm_mfma_kernel(
    const bf16_t* __restrict__ A,    // (M,K)
    const bf16_t* __restrict__ W,    // (N,K)
    const float* __restrict__ bias,  // (N) or (M) if BIASROW
    const float* __restrict__ res,   // (M,N) or nullptr
    float* __restrict__ Cf,          // fp32 out (if !BF16OUT)
    bf16_t* __restrict__ Cb,         // bf16 out (if BF16OUT)
    int M, int N, int K)
{
    __shared__ __align__(16) bf16_t As[128 * 32];
    __shared__ __align__(16) bf16_t Ws[128 * 32];
    const int tid  = threadIdx.x;
    const int bm   = blockIdx.y * 128;
    const int bn   = blockIdx.x * 128;
    const int lane = tid & 63;
    const int wave = tid >> 6;
    const int wr   = (wave >> 1) * 64;   // wave row offset within tile
    const int wc   = (wave & 1) * 64;    // wave col offset within tile

    const int lrow = tid >> 2;           // 0..63
    const int lcol = (tid & 3) * 8;      // 0,8,16,24 (bf16 elements)

    const bf16_t* Ag = A + (size_t)(bm + lrow) * K + lcol;
    const bf16_t* Wg = W + (size_t)(bn + lrow) * K + lcol;
    bf16_t* AsL0 = As + lrow * 32 + lcol;
    bf16_t* AsL1 = As + (64 + lrow) * 32 + lcol;
    bf16_t* WsL0 = Ws + lrow * 32 + lcol;
    bf16_t* WsL1 = Ws + (64 + lrow) * 32 + lcol;

    f32x4 acc[4][4] = {};

    const int fr = lane & 15;            // m (or n) within 16-tile
    const int fc = (lane >> 4) * 8;      // k offset (quad*8)

    for (int k0 = 0; k0 < K; k0 += 32) {
        GLD_LDS16(Ag + k0,                AsL0);
        GLD_LDS16(Ag + (size_t)64*K + k0, AsL1);
        GLD_LDS16(Wg + k0,                WsL0);
        GLD_LDS16(Wg + (size_t)64*K + k0, WsL1);
        __syncthreads();

        bf16x8 af[4], wf[4];
        #pragma unroll
        for (int i = 0; i < 4; ++i)
            af[i] = *(const bf16x8*)(As + (wr + i*16 + fr) * 32 + fc);
        #pragma unroll
        for (int j = 0; j < 4; ++j)
            wf[j] = *(const bf16x8*)(Ws + (wc + j*16 + fr) * 32 + fc);
        #pragma unroll
        for (int i = 0; i < 4; ++i)
            #pragma unroll
            for (int j = 0; j < 4; ++j)
                acc[i][j] = __builtin_amdgcn_mfma_f32_16x16x32_bf16(
                    af[i], wf[j], acc[i][j], 0, 0, 0);
        __syncthreads();
    }

    // Epilogue. C/D layout: col = lane&15, row = (lane>>4)*4 + reg
    const int fq = lane >> 4;
    #pragma unroll
    for (int i = 0; i < 4; ++i) {
        const int row0 = bm + wr + i*16 + fq*4;
        #pragma unroll
        for (int j = 0; j < 4; ++j) {
            const int col = bn + wc + j*16 + fr;
            const float bcol = BIASROW ? 0.0f : bias[col];
            #pragma unroll
            for (int r = 0; r < 4; ++r) {
                float v = acc[i][j][r] + (BIASROW ? bias[row0 + r] : bcol);
                if constexpr (EPI == 2) v = gelu_tanh(v);
                if constexpr (EPI == 1) v += res[(size_t)(row0 + r) * N + col];
                if constexpr (BF16OUT)
                    Cb[(size_t)(row0 + r) * N + col] = (bf16_t)v;
                else
                    Cf[(size_t)(row0 + r) * N + col] = v;
            }
        }
    }
}

// ---------------------------------------------------------------------------
// Depthwise causal k=3 short filter on u_t (3D, M) channel-major, producing
//   x0t (D, M)  (layout (D,B,L)) = conv channels [0,D)
//   vin (D, M)  (layout (D,B,L)) = conv[2D..3D) * conv[D..2D)
// One block per d; fully coalesced reads and writes, no LDS.
// ---------------------------------------------------------------------------
__global__ __launch_bounds__(256) void shortfilter_kernel(
    const float* __restrict__ ut, const float* __restrict__ sw,
    const float* __restrict__ sb, float* __restrict__ x0t,
    float* __restrict__ vin)
{
    const int d = blockIdx.x;             // 0..1023
    const int c0 = d, c1 = DD + d, c2 = 2 * DD + d;
    const float w0a = sw[c0*3+0], w0b = sw[c0*3+1], w0c = sw[c0*3+2], b0 = sb[c0];
    const float w1a = sw[c1*3+0], w1b = sw[c1*3+1], w1c = sw[c1*3+2], b1 = sb[c1];
    const float w2a = sw[c2*3+0], w2b = sw[c2*3+1], w2c = sw[c2*3+2], b2 = sb[c2];
    const float* r0 = ut + (size_t)c0 * MM;
    const float* r1 = ut + (size_t)c1 * MM;
    const float* r2 = ut + (size_t)c2 * MM;
    float* o0 = x0t + (size_t)d * MM;
    float* o1 = vin + (size_t)d * MM;
    for (int m = threadIdx.x; m < MM; m += 256) {
        const int l = m & (LL - 1);
        float v0 = w0c * r0[m] + b0;
        float v1 = w1c * r1[m] + b1;
        float v2 = w2c * r2[m] + b2;
        if (l >= 1) {
            v0 += w0b * r0[m-1]; v1 += w1b * r1[m-1]; v2 += w2b * r2[m-1];
        }
        if (l >= 2) {
            v0 += w0a * r0[m-2]; v1 += w1a * r1[m-2]; v2 += w2a * r2[m-2];
        }
        o0[m] = v0;
        o1[m] = v2 * v1;
    }
}

// ---------------------------------------------------------------------------
// Implicit filter MLP -> kfilt (D,L). One block per position l.
// ---------------------------------------------------------------------------
__global__ __launch_bounds__(256) void filtergen_kernel(
    const float* __restrict__ w1, const float* __restrict__ b1,
    const float* __restrict__ f1, const float* __restrict__ w2,
    const float* __restrict__ b2, const float* __restrict__ f2,
    const float* __restrict__ w3, float* __restrict__ kfilt)
{
    __shared__ float h1[64];
    __shared__ float h2[64];
    const int l = blockIdx.x;
    const float t = (float)l / (float)(LL - 1);
    const float ang = 1e-4f * 6.283185307179586f * (float)l / (float)LL;
    const float z0 = t, z1 = cosf(ang), z2 = -sinf(ang);
    const int tid = threadIdx.x;
    if (tid < 64) {
        float s = w1[tid*3+0]*z0 + w1[tid*3+1]*z1 + w1[tid*3+2]*z2 + b1[tid];
        h1[tid] = sinf(f1[tid] * s);
    }
    __syncthreads();
    if (tid < 64) {
        float s = b2[tid];
        #pragma unroll 8
        for (int j = 0; j < 64; ++j) s += w2[tid*64+j] * h1[j];
        h2[tid] = sinf(f2[tid] * s);
    }
    __syncthreads();
    const float min_decay = -3.0701134573253944f;   // ln(1e-2)/1.5
    const float max_decay = -15.350567286626972f;   // ln(1e-2)/0.3
    #pragma unroll
    for (int i = 0; i < 4; ++i) {
        const int d = tid + (i << 8);
        float s = 0.f;
        #pragma unroll 8
        for (int j = 0; j < 64; ++j) s += w3[d*64+j] * h2[j];
        const float delta = fabsf(min_decay + (max_decay - min_decay) * (float)d / (float)(DD - 1));
        kfilt[(size_t)d * LL + l] = s * expf(-t * delta);
    }
}

// ---------------------------------------------------------------------------
// 4096-point complex Stockham radix-4 FFT in LDS (6 stages, autosort).
// SIGN = -1 forward, +1 unnormalized inverse. NT threads, 1024/NT
// butterflies each. All LDS indices pass through SWZ (bank uniformity).
// ---------------------------------------------------------------------------
template<int NT, int SIGN>
__device__ __forceinline__ int fft4096_r4(float2 (*bufs)[4096], int cur)
{
    constexpr int NB = 1024 / NT;
    const float fsign = (float)SIGN;
    #pragma unroll
    for (int t = 0; t < 6; ++t) {
        const int ls = 2 * t;                        // log2(stride)
        const float theta = fsign * 6.283185307179586f / (float)(4096 >> ls);
        float2* __restrict__ src = bufs[cur];
        float2* __restrict__ dst = bufs[cur ^ 1];
        #pragma unroll
        for (int it = 0; it < NB; ++it) {
            const int idx = (int)threadIdx.x + it * NT;   // 0..1023
            const int p = idx >> ls;
            const int q = idx & ((1 << ls) - 1);
            const float2 a0 = src[SWZ(idx)];
            const float2 a1 = src[SWZ(idx + 1024)];
            const float2 a2 = src[SWZ(idx + 2048)];
            const float2 a3 = src[SWZ(idx + 3072)];
            float sn, cs;
            __sincosf(theta * (float)p, &sn, &cs);
            const float2 W  = make_float2(cs, sn);
            const float2 W2 = make_float2(cs*cs - sn*sn, 2.0f*cs*sn);
            const float2 u0 = make_float2(a0.x + a2.x, a0.y + a2.y);
            const float2 u1 = make_float2(a1.x + a3.x, a1.y + a3.y);
            const float2 t2 = make_float2(a0.x - a2.x, a0.y - a2.y);
            const float2 t3 = make_float2(a1.x - a3.x, a1.y - a3.y);
            const float2 u2 = cmul(W, t2);
            const float2 it3 = make_float2(-fsign * t3.y, fsign * t3.x);
            const float2 u3 = cmul(W, it3);
            const int o = q + (p << (ls + 2));
            dst[SWZ(o)]             = make_float2(u0.x + u1.x, u0.y + u1.y);
            dst[SWZ(o + (1 << ls))] = make_float2(u2.x + u3.x, u2.y + u3.y);
            dst[SWZ(o + (2 << ls))] = cmul(make_float2(u0.x - u1.x, u0.y - u1.y), W2);
            dst[SWZ(o + (3 << ls))] = cmul(make_float2(u2.x - u3.x, u2.y - u3.y), W2);
        }
        __syncthreads();
        cur ^= 1;
    }
    return cur;
}

// ---------------------------------------------------------------------------
// FFT of filter rows, two real rows per block (z = k_{2d} + i*k_{2d+1}).
// Half-spectra extracted via conjugate symmetry; /4096 folded in.
// ---------------------------------------------------------------------------
__global__ __launch_bounds__(512) void kfft_kernel(
    const float* __restrict__ kfilt, float2* __restrict__ Kf)
{
    __shared__ float2 fb[2][4096];
    const int d0 = blockIdx.x * 2;
    const float* k0 = kfilt + (size_t)d0 * LL;
    const float* k1 = k0 + LL;
    const float inv = 1.0f / 4096.0f;
    const int tid = threadIdx.x;
    for (int i = tid; i < 2048; i += 512) {
        fb[0][SWZ(i)]        = make_float2(k0[i] * inv, k1[i] * inv);
        fb[0][SWZ(i + 2048)] = make_float2(0.f, 0.f);
    }
    __syncthreads();
    const int cur = fft4096_r4<512, -1>(fb, 0);
    float2* o0 = Kf + (size_t)d0 * KF_STRIDE;
    float2* o1 = o0 + KF_STRIDE;
    for (int k = tid; k <= 2048; k += 512) {
        const float2 z1 = fb[cur][SWZ(k)];
        const float2 z2 = fb[cur][SWZ((4096 - k) & 4095)];
        o0[k] = make_float2(0.5f * (z1.x + z2.x), 0.5f * (z1.y - z2.y));
        o1[k] = make_float2(0.5f * (z1.y + z2.y), 0.5f * (z2.x - z1.x));
    }
}

// ---------------------------------------------------------------------------
// Long conv, two real rows per block: z = v1 + i*v2, filter k is REAL.
// vio layout (D, B, L): row r = d*B + b. Block blk handles rows 2blk, 2blk+1
// (same d = blk>>1, adjacent b). In place + bias.
// ---------------------------------------------------------------------------
__global__ __launch_bounds__(512) void fftconv_kernel(
    float* __restrict__ vio, const float2* __restrict__ Kf,
    const float* __restrict__ fbias)
{
    __shared__ float2 fb[2][4096];
    const int blk = blockIdx.x;          // [0, 2048)
    const int d   = blk >> 1;
    float* v1 = vio + (size_t)(2 * blk) * LL;
    float* v2 = v1 + LL;
    const int tid = threadIdx.x;
    for (int i = tid; i < 2048; i += 512) {
        fb[0][SWZ(i)]        = make_float2(v1[i], v2[i]);
        fb[0][SWZ(i + 2048)] = make_float2(0.f, 0.f);
    }
    __syncthreads();
    int cur = fft4096_r4<512, -1>(fb, 0);
    const float2* kf = Kf + (size_t)d * KF_STRIDE;
    for (int i = tid; i < 4096; i += 512) {
        const float2 a = fb[cur][SWZ(i)];
        float2 k;
        if (i <= 2048) k = kf[i];
        else { const float2 t = kf[4096 - i]; k = make_float2(t.x, -t.y); }
        fb[cur][SWZ(i)] = cmul(a, k);
    }
    __syncthreads();
    cur = fft4096_r4<512, 1>(fb, cur);
    const float bias = fbias[d];
    for (int i = tid; i < 2048; i += 512) {
        const float2 zy = fb[cur][SWZ(i)];
        v1[i] = zy.x + bias * v1[i];
        v2[i] = zy.y + bias * v2[i];
    }
}

// ---------------------------------------------------------------------------
// gated_bf16(B,L,D) = bf16( y(D,B,L) * x0t(D,B,L) )  -- LDS 32x32 transpose
// ---------------------------------------------------------------------------
__global__ __launch_bounds__(256) void gate_transpose_kernel(
    const float* __restrict__ y, const float* __restrict__ x0t,
    bf16_t* __restrict__ g)
{
    __shared__ float tile[32][33];
    const int b  = blockIdx.z;
    const int l0 = blockIdx.x * 32;
    const int d0 = blockIdx.y * 32;
    const int tx  = threadIdx.x & 31;
    const int tyb = threadIdx.x >> 5;    // 0..7
    #pragma unroll
    for (int i = 0; i < 4; ++i) {
        const int dy = tyb + i * 8;
        const size_t src = ((size_t)(d0 + dy) * BB + b) * LL + l0 + tx;
        tile[dy][tx] = y[src] * x0t[src];
    }
    __syncthreads();
    #pragma unroll
    for (int i = 0; i < 4; ++i) {
        const int ly = tyb + i * 8;
        g[((size_t)(b * LL + l0 + ly)) * DD + d0 + tx] = (bf16_t)tile[tx][ly];
    }
}

// ---------------------------------------------------------------------------
// Launch
// ---------------------------------------------------------------------------
extern "C" void kernel_launch(void* const* d_in, const int* in_sizes, int n_in,
                              void* d_out, int out_size, void* d_ws, size_t ws_size,
                              hipStream_t stream)
{
    (void)in_sizes; (void)n_in; (void)out_size; (void)ws_size;
    const float* x   = (const float*)d_in[0];
    const float* nw0 = (const float*)d_in[1];
    const float* ipw = (const float*)d_in[2];
    const float* ipb = (const float*)d_in[3];
    const float* sfw = (const float*)d_in[4];
    const float* sfb = (const float*)d_in[5];
    const float* w1  = (const float*)d_in[6];
    const float* b1  = (const float*)d_in[7];
    const float* f1  = (const float*)d_in[8];
    const float* w2  = (const float*)d_in[9];
    const float* b2  = (const float*)d_in[10];
    const float* f2  = (const float*)d_in[11];
    const float* w3  = (const float*)d_in[12];
    const float* fbv = (const float*)d_in[13];
    const float* opw = (const float*)d_in[14];
    const float* opb = (const float*)d_in[15];
    const float* nw1 = (const float*)d_in[16];
    const float* fw1 = (const float*)d_in[17];
    const float* fb1 = (const float*)d_in[18];
    const float* fw2 = (const float*)d_in[19];
    const float* fb2 = (const float*)d_in[20];
    float* out = (float*)d_out;

    float* ws = (float*)d_ws;
    // Region 0: u_t (3D, M) fp32 = 25,165,824 f. After shortfilter consumes
    // u_t, the region holds: gated_bf16 (8M bf16), h (8M f), mid_bf16 (16M bf16)
    float*  ut     = ws;
    bf16_t* gatedb = (bf16_t*)ws;                       // 8,388,608 bf16
    float*  h      = ws + 4194304;                      // 8,388,608 f
    bf16_t* midb   = (bf16_t*)(ws + 12582912);          // 16,777,216 bf16
    bf16_t* xnb    = (bf16_t*)(ws + 25165824);          // 8M bf16 (also hn later)
    float*  x0t    = ws + 29360128;                     // 8,388,608 f (D,B,L)
    float*  vio    = ws + 37748736;                     // 8,388,608 f (D,B,L)
    float*  kfilt  = ws + 46137344;                     // 2,097,152 f
    float2* Kf     = (float2*)(ws + 48234496);          // 1024 x KF_STRIDE cplx
    bf16_t* ipwb   = (bf16_t*)(ws + 52445184);          // 3,145,728 bf16
    bf16_t* opwb   = ipwb + 3145728;                    // 1,048,576 bf16
    bf16_t* fw1b   = opwb + 1048576;                    // 2,097,152 bf16
    bf16_t* fw2b   = fw1b + 2097152;                    // 2,097,152 bf16
    // total: 56,639,488 f = 226.6 MB

    // 0. weight casts
    cast_bf16_kernel<<<3072*1024/1024, 256, 0, stream>>>(ipw, ipwb);
    cast_bf16_kernel<<<1024*1024/1024, 256, 0, stream>>>(opw, opwb);
    cast_bf16_kernel<<<2048*1024/1024, 256, 0, stream>>>(fw1, fw1b);
    cast_bf16_kernel<<<2048*1024/1024, 256, 0, stream>>>(fw2, fw2b);
    // 1. implicit filter -> kfilt (D,L);  Kf = FFT(kfilt)/4096 (half spectrum)
    filtergen_kernel<<<LL, 256, 0, stream>>>(w1, b1, f1, w2, b2, f2, w3, kfilt);
    kfft_kernel<<<DD/2, 512, 0, stream>>>(kfilt, Kf);
    // 2. xn = bf16(rmsnorm(x, norm_in_w))
    rmsnorm_bf16_kernel<<<MM, 256, 0, stream>>>(x, nw0, xnb);
    // 3. u_t = in_proj_w @ xn^T + b (transposed output: rows = channels)
    //    M'=3072 (channels), N'=8192 (tokens), K=1024, bias per row.
    gemm_mfma_kernel<0, false, true><<<dim3(MM/128, 3072/128), 256, 0, stream>>>(
        ipwb, xnb, ipb, nullptr, ut, nullptr, 3*DD, MM, DD);
    // 4. short filter -> x0t (D,B,L), vin (D,B,L); coalesced both ways
    shortfilter_kernel<<<DD, 256, 0, stream>>>(ut, sfw, sfb, x0t, vio);
    // 5. vio <- causal_conv(vio, k) + filter_bias * vio   (2 rows per block)
    fftconv_kernel<<<BB*DD/2, 512, 0, stream>>>(vio, Kf, fbv);
    // 6. gated_bf16(B,L,D) = y * x0
    gate_transpose_kernel<<<dim3(LL/32, DD/32, BB), 256, 0, stream>>>(vio, x0t, gatedb);
    // 7. h = gated @ out_proj_w^T + b + x   (M=8192, N=1024, K=1024)
    gemm_mfma_kernel<1, false><<<dim3(DD/128, MM/128), 256, 0, stream>>>(
        gatedb, opwb, opb, x, h, nullptr, MM, DD, DD);
    // 8. hn = bf16(rmsnorm(h, norm_w))
    rmsnorm_bf16_kernel<<<MM, 256, 0, stream>>>(h, nw1, xnb);
    // 9. mid = bf16(gelu(hn @ ffn_w1^T + b))  (M=8192, N=2048, K=1024)
    gemm_mfma_kernel<2, true><<<dim3(2*DD/128, MM/128), 256, 0, stream>>>(
        xnb, fw1b, fb1, nullptr, nullptr, midb, MM, 2*DD, DD);
    // 10. out = mid @ ffn_w2^T + b + h      (M=8192, N=1024, K=2048)
    gemm_mfma_kernel<1, false><<<dim3(DD/128, MM/128), 256, 0, stream>>>(
        midb, fw2b, fb2, h, out, nullptr, MM, DD, 2*DD);
}